// Round 1
// baseline (178.145 us; speedup 1.0000x reference)
//
#include <hip/hip_runtime.h>
#include <stdint.h>

#define B_N   1024
#define D_DIM 512
#define H_DIM 512
#define A_DIM 18
#define T_N   64
#define HTILE 256
#define SMAX  32   // sample slots per block pass

// Inline task_id dtype detection (int32 vs int64), executed by one full wave.
__device__ __forceinline__ bool taskid_is_int32(const int* raw, int lane) {
    int probe = raw[lane];
    unsigned long long odd = __ballot((lane & 1) && probe != 0);
    return odd != 0ull;
}

// ---------------- K2: fc1 partial GEMM, grid (task, htile, ksplit) ----------------
// v2 structure: threads own H columns (col = htile*256 + tid), samples are the
// register-blocked inner loop. w1 tile is fetched exactly ONCE per block
// (previously all 4 waves loaded identical data), double-buffered 16-deep.
// Arithmetic order per (sample, col) is unchanged vs the validated version:
// d ascending, fmaf chain -> hpre is bit-identical.
template <int KSP>
__global__ __launch_bounds__(256) void fc1_kernel(const float* __restrict__ xs,
                                                  const float* __restrict__ w1,
                                                  const int* __restrict__ raw,
                                                  float* __restrict__ hpre) {
    constexpr int DK = D_DIM / KSP;      // 128 for KSP=4
    constexpr int NCHUNK = DK / 16;
    int task  = blockIdx.x;
    int htile = blockIdx.y;
    int ksp   = blockIdx.z;
    int tid   = threadIdx.x;
    int lane  = tid & 63;

    __shared__ int slist[B_N];           // worst case: all samples one task
    __shared__ int s_n;
    __shared__ __align__(16) float xlds[SMAX][DK];

    if (tid < 64) {
        bool is32 = taskid_is_int32(raw, lane);
        int base = 0;
        for (int c = 0; c < B_N; c += 64) {
            int id = is32 ? raw[c + lane] : raw[2 * (c + lane)];
            unsigned long long m = __ballot(id == task);
            if (id == task) {
                unsigned long long below = m & ((1ull << lane) - 1ull);
                slist[base + __popcll(below)] = c + lane;
            }
            base += __popcll(m);
        }
        if (lane == 0) s_n = base;
    }
    __syncthreads();
    int n = s_n;
    if (n == 0) return;

    int col = htile * HTILE + tid;       // each thread owns one H column
    int d0  = ksp * DK;
    const float* wcol = w1 + ((size_t)task * D_DIM + d0) * H_DIM + col;
    float* hout = hpre + (size_t)ksp * ((size_t)B_N * H_DIM) + col;

    for (int sb = 0; sb < n; sb += SMAX) {
        int ns  = min(SMAX, n - sb);
        int nsr = (ns + 7) & ~7;         // round up to slot-group of 8

        // stage xs rows (coalesced float4), zero-fill padded rows
        for (int idx = tid; idx < nsr * (DK / 4); idx += 256) {
            int sl = idx >> 5;           // DK/4 == 32 for KSP=4
            int f  = idx & (DK / 4 - 1);
            float4 v = make_float4(0.f, 0.f, 0.f, 0.f);
            if (sl < ns) {
                int smp = slist[sb + sl];
                v = *(const float4*)(xs + (size_t)smp * D_DIM + d0 + 4 * f);
            }
            *(float4*)(&xlds[sl][4 * f]) = v;
        }
        __syncthreads();

        float acc[SMAX];
#pragma unroll
        for (int j = 0; j < SMAX; ++j) acc[j] = 0.f;

        float wa[16], wb[16];

#define LOADW(buf, cc)                                                        \
        _Pragma("unroll")                                                     \
        for (int u = 0; u < 16; ++u)                                          \
            buf[u] = wcol[(size_t)((cc) * 16 + u) * H_DIM];

#define COMPW(buf, cc) do {                                                   \
        int dbase = (cc) * 16;                                                \
        _Pragma("unroll")                                                     \
        for (int jb = 0; jb < SMAX / 8; ++jb) {                               \
            if (jb * 8 < nsr) {                                               \
                _Pragma("unroll")                                             \
                for (int jj = 0; jj < 8; ++jj) {                              \
                    int j = jb * 8 + jj;                                      \
                    float4 x0 = *(const float4*)(&xlds[j][dbase]);            \
                    float4 x1 = *(const float4*)(&xlds[j][dbase + 4]);        \
                    float4 x2 = *(const float4*)(&xlds[j][dbase + 8]);        \
                    float4 x3 = *(const float4*)(&xlds[j][dbase + 12]);       \
                    float xv[16] = {x0.x, x0.y, x0.z, x0.w,                   \
                                    x1.x, x1.y, x1.z, x1.w,                   \
                                    x2.x, x2.y, x2.z, x2.w,                   \
                                    x3.x, x3.y, x3.z, x3.w};                  \
                    _Pragma("unroll")                                         \
                    for (int u = 0; u < 16; ++u)                              \
                        acc[j] = fmaf(xv[u], buf[u], acc[j]);                 \
                }                                                             \
            }                                                                 \
        }                                                                     \
    } while (0)

        LOADW(wa, 0);
#pragma unroll
        for (int c = 0; c < NCHUNK; ++c) {
            if ((c & 1) == 0) {
                if (c + 1 < NCHUNK) { LOADW(wb, c + 1); }
                COMPW(wa, c);
            } else {
                if (c + 1 < NCHUNK) { LOADW(wa, c + 1); }
                COMPW(wb, c);
            }
        }
#undef LOADW
#undef COMPW

#pragma unroll
        for (int j = 0; j < SMAX; ++j) {
            if (j < ns) {
                int smp = slist[sb + j];
                hout[(size_t)smp * H_DIM] = acc[j];
            }
        }
        __syncthreads();
    }
}

// ---------------- threefry2x32, partitionable counter mode, key = (0, 1) --------
// (validated bit-exact in round 4 — do not touch)
__device__ __forceinline__ uint32_t rotl32(uint32_t x, int r) {
    return (x << r) | (x >> (32 - r));
}

__device__ __forceinline__ uint32_t threefry_bits_part(uint32_t i) {
    uint32_t x0 = 0u;        // i >> 32 for i < 2^32
    uint32_t x1 = i;
    const uint32_t ks0 = 0u, ks1 = 1u, ks2 = 0x1BD11BDAu ^ 0u ^ 1u;
    x0 += ks0; x1 += ks1;
#define TFR(r) { x0 += x1; x1 = rotl32(x1, (r)); x1 ^= x0; }
    TFR(13) TFR(15) TFR(26) TFR(6)
    x0 += ks1; x1 += ks2 + 1u;
    TFR(17) TFR(29) TFR(16) TFR(24)
    x0 += ks2; x1 += ks0 + 2u;
    TFR(13) TFR(15) TFR(26) TFR(6)
    x0 += ks0; x1 += ks1 + 3u;
    TFR(17) TFR(29) TFR(16) TFR(24)
    x0 += ks1; x1 += ks2 + 4u;
    TFR(13) TFR(15) TFR(26) TFR(6)
    x0 += ks2; x1 += ks0 + 5u;
#undef TFR
    return x0 ^ x1;
}

// ---------------- K3: relu + fc2 + log_softmax + gumbel sample, one wave/sample ----
// UNCHANGED from the validated version (isolates the fc1 A/B; outputs bit-identical).
template <int KSP>
__global__ __launch_bounds__(64) void head_kernel(const int* __restrict__ raw,
                                                  const float* __restrict__ hpre,
                                                  const float* __restrict__ b1,
                                                  const float* __restrict__ w2,
                                                  const float* __restrict__ b2,
                                                  float* __restrict__ out) {
    __shared__ __align__(16) float w2l[H_DIM * A_DIM];   // 9216 floats = 36 KB
    __shared__ float red[16][A_DIM];
    __shared__ float logits_lds[A_DIM];

    int s = blockIdx.x;
    int lane = threadIdx.x;
    bool is32 = taskid_is_int32(raw, lane);
    int t = is32 ? raw[s] : raw[2 * s];

    // ---- stage w2[t] into LDS, coalesced: 9216 floats = 36 float4 per lane ----
    const float4* g4 = (const float4*)(w2 + (size_t)t * (H_DIM * A_DIM));
    float4* l4 = (float4*)w2l;
#pragma unroll
    for (int i = 0; i < (H_DIM * A_DIM) / (64 * 4); ++i)   // 36 iters
        l4[i * 64 + lane] = g4[i * 64 + lane];

    // ---- h = relu(sum_k partial_k + b1) (overlaps with staging latency) ----
    float hreg[H_DIM / 64];
#pragma unroll
    for (int k = 0; k < H_DIM / 64; ++k) {
        int h = lane + 64 * k;
        size_t p = (size_t)s * H_DIM + h;
        float v = b1[(size_t)t * H_DIM + h];
#pragma unroll
        for (int q = 0; q < KSP; ++q)
            v += hpre[(size_t)q * ((size_t)B_N * H_DIM) + p];
        hreg[k] = fmaxf(v, 0.f);
    }
    __syncthreads();   // w2l visible (single wave: cheap)

    // ---- per-lane partial logits from LDS ----
    float la[A_DIM];
#pragma unroll
    for (int a = 0; a < A_DIM; ++a) la[a] = 0.f;
#pragma unroll
    for (int k = 0; k < H_DIM / 64; ++k) {
        int h = lane + 64 * k;
        const float2* row = (const float2*)&w2l[h * A_DIM];   // 72 B rows: 8 B aligned
        float hk = hreg[k];
#pragma unroll
        for (int a2 = 0; a2 < A_DIM / 2; ++a2) {
            float2 ww = row[a2];
            la[2 * a2]     = fmaf(hk, ww.x, la[2 * a2]);
            la[2 * a2 + 1] = fmaf(hk, ww.y, la[2 * a2 + 1]);
        }
    }

    // ---- reduce 64 partials: shfl_xor(1,2) -> 16 rows -> LDS -> 18-lane sum ----
#pragma unroll
    for (int a = 0; a < A_DIM; ++a) {
        la[a] += __shfl_xor(la[a], 1);
        la[a] += __shfl_xor(la[a], 2);
    }
    if ((lane & 3) == 0) {
        int g = lane >> 2;
#pragma unroll
        for (int a = 0; a < A_DIM; ++a) red[g][a] = la[a];
    }
    __syncthreads();
    if (lane < A_DIM) {
        float sum = b2[(size_t)t * A_DIM + lane];
#pragma unroll
        for (int g = 0; g < 16; ++g) sum += red[g][lane];
        logits_lds[lane] = sum;
    }
    __syncthreads();

    // ---- tail: identical to the validated round-4 code ----
    float lg = (lane < A_DIM) ? logits_lds[lane] : -INFINITY;

    float z = -INFINITY;
    if (lane < A_DIM) {
        uint32_t bits = threefry_bits_part((uint32_t)(s * A_DIM + lane));
        float f = __uint_as_float(0x3f800000u | (bits >> 9)) - 1.0f;
        float u = fmaxf(f, 1.17549435e-38f);   // jnp.finfo(f32).tiny
        float g = -logf(-logf(u));
        z = lg + g;
    }
    int idx = lane;
#pragma unroll
    for (int o = 1; o < 64; o <<= 1) {
        float oz = __shfl_xor(z, o);
        int   oi = __shfl_xor(idx, o);
        if (oz > z || (oz == z && oi < idx)) { z = oz; idx = oi; }
    }

    float mx = lg;
#pragma unroll
    for (int o = 1; o < 64; o <<= 1) mx = fmaxf(mx, __shfl_xor(mx, o));
    float e = (lane < A_DIM) ? expf(lg - mx) : 0.f;
#pragma unroll
    for (int o = 1; o < 64; o <<= 1) e += __shfl_xor(e, o);
    float lse = mx + logf(e);
    float lp = lg - lse;
    float c = (lane < A_DIM) ? expf(lp) * lp : 0.f;
#pragma unroll
    for (int o = 1; o < 64; o <<= 1) c += __shfl_xor(c, o);

    if (lane == 0) {
        out[s]             = (float)idx;            // action
        out[B_N + s]       = logits_lds[idx] - lse; // log_prob
        out[2 * B_N + s]   = -c;                    // entropy
    }
}

extern "C" void kernel_launch(void* const* d_in, const int* in_sizes, int n_in,
                              void* d_out, int out_size, void* d_ws, size_t ws_size,
                              hipStream_t stream) {
    const float* xs      = (const float*)d_in[0];
    const int*   traw    = (const int*)d_in[1];   // int32 or int64 — detected on device
    const float* w1      = (const float*)d_in[2];
    const float* b1      = (const float*)d_in[3];
    const float* w2      = (const float*)d_in[4];
    const float* b2      = (const float*)d_in[5];
    float* out = (float*)d_out;
    char*  ws  = (char*)d_ws;

    const size_t part_bytes = (size_t)B_N * H_DIM * sizeof(float);  // 2 MB per K-split partial

    // Pick K-split by available workspace (constant per process -> graph-safe).
    int ksp = 4;
    if (ws_size < 4 * part_bytes) ksp = 2;
    if (ws_size < 2 * part_bytes) ksp = 1;

    float* hpre = (float*)ws;

    if (ksp == 4) {
        fc1_kernel<4><<<dim3(T_N, 2, 4), 256, 0, stream>>>(xs, w1, traw, hpre);
        head_kernel<4><<<B_N, 64, 0, stream>>>(traw, hpre, b1, w2, b2, out);
    } else if (ksp == 2) {
        fc1_kernel<2><<<dim3(T_N, 2, 2), 256, 0, stream>>>(xs, w1, traw, hpre);
        head_kernel<2><<<B_N, 64, 0, stream>>>(traw, hpre, b1, w2, b2, out);
    } else {
        fc1_kernel<1><<<dim3(T_N, 2, 1), 256, 0, stream>>>(xs, w1, traw, hpre);
        head_kernel<1><<<B_N, 64, 0, stream>>>(traw, hpre, b1, w2, b2, out);
    }
}